// Round 10
// baseline (298.734 us; speedup 1.0000x reference)
//
#include <hip/hip_runtime.h>
#include <hip/hip_bf16.h>

// Problem constants (B=4, T=2048, C=1024, H=16, HD=64)
#define BB 4
#define TT 2048
#define CC 1024
#define HH 16
#define HD 64

typedef _Float16 half8 __attribute__((ext_vector_type(8)));
typedef _Float16 half4 __attribute__((ext_vector_type(4)));
typedef _Float16 half2_t __attribute__((ext_vector_type(2)));
typedef __fp16 fp16x2 __attribute__((ext_vector_type(2)));
typedef float floatx4 __attribute__((ext_vector_type(4)));
typedef float floatx16 __attribute__((ext_vector_type(16)));
typedef int intx2 __attribute__((ext_vector_type(2)));
typedef int intx4 __attribute__((ext_vector_type(4)));

// async global->LDS, 16B per lane (dest = wave-uniform base + lane*16)
__device__ __forceinline__ void async_cp16(const void* g, void* l) {
    __builtin_amdgcn_global_load_lds(
        (const __attribute__((address_space(1))) unsigned int*)g,
        (__attribute__((address_space(3))) unsigned int*)l,
        16, 0, 0);
}

// raw v_exp_f32 — args <= 8 (defer-max THR) so no overflow; very negative
// args underflow to 0 in HW which is exactly softmax semantics.
__device__ __forceinline__ float exp2_raw(float x) {
    return __builtin_amdgcn_exp2f(x);
}

// pack 2 f32 -> dword of 2 fp16 via v_cvt_pkrtz
__device__ __forceinline__ int pkh(float a, float b) {
    fp16x2 v = __builtin_amdgcn_cvt_pkrtz(a, b);
    return __builtin_bit_cast(int, v);
}

// max over a f32x16 accumulator, max3-friendly
__device__ __forceinline__ float maxv16(floatx16 s) {
    float a0 = fmaxf(fmaxf(s[0], s[1]), s[2]);
    float a1 = fmaxf(fmaxf(s[3], s[4]), s[5]);
    float a2 = fmaxf(fmaxf(s[6], s[7]), s[8]);
    float a3 = fmaxf(fmaxf(s[9], s[10]), s[11]);
    float a4 = fmaxf(fmaxf(s[12], s[13]), s[14]);
    float b0 = fmaxf(fmaxf(a0, a1), a2);
    float b1 = fmaxf(fmaxf(a3, a4), s[15]);
    return fmaxf(b0, b1);
}

// Assemble one 16-key B-frag (32x32x16, 8 fp16) from 4 cvtpk dwords.
// (verified rounds 5-9: passes absmax)
__device__ __forceinline__ half8 assembleF(int a, int b, int c, int d) {
    intx2 s1 = __builtin_amdgcn_permlane32_swap(a, c, false, false);
    intx2 s2 = __builtin_amdgcn_permlane32_swap(b, d, false, false);
    intx4 w = {s1[0], s2[0], s1[1], s2[1]};
    return __builtin_bit_cast(half8, w);
}

// ---------------------------------------------------------------------------
// fused fp32 -> fp16 conversion for x, W_attn, W_proj in ONE launch.
// ---------------------------------------------------------------------------
#define NX  (BB * TT * CC)        // 8388608
#define NWA (3 * CC * CC)         // 3145728
#define NWP (CC * CC)             // 1048576
__global__ void cvt_all(const float* __restrict__ x, const float* __restrict__ wa,
                        const float* __restrict__ wp,
                        _Float16* __restrict__ xh, _Float16* __restrict__ wah,
                        _Float16* __restrict__ wph) {
    int i = (blockIdx.x * blockDim.x + threadIdx.x) * 8;
    const float* src;
    _Float16* dst;
    int j;
    if (i < NX)            { src = x;  dst = xh;  j = i; }
    else if (i < NX + NWA) { src = wa; dst = wah; j = i - NX; }
    else                   { src = wp; dst = wph; j = i - NX - NWA; }
    float4 v0 = *(const float4*)(src + j);
    float4 v1 = *(const float4*)(src + j + 4);
    half8 h;
    h[0] = (_Float16)v0.x; h[1] = (_Float16)v0.y; h[2] = (_Float16)v0.z; h[3] = (_Float16)v0.w;
    h[4] = (_Float16)v1.x; h[5] = (_Float16)v1.y; h[6] = (_Float16)v1.z; h[7] = (_Float16)v1.w;
    *(half8*)(dst + j) = h;
}

// ---------------------------------------------------------------------------
// NT GEMM: 128x128 tile, BK=64 + T1 XCD swizzle (round-9 proven).
// EPI=0: scatter -> Q(scaled)/K fp16 [B*H,T,64]; V TRANSPOSED [B*H,64,T]
//        (zero-cost transpose at producer: stores are scalar scatter anyway;
//         lets attn stage V^T row-major via global_load_lds like K)
// EPI=1: fp32 -> c_out[m*N+n]
// ---------------------------------------------------------------------------
template <int EPI>
__global__ __launch_bounds__(256) void hgemm_nt(
    const _Float16* __restrict__ A, const _Float16* __restrict__ Bw,
    const float* __restrict__ bias,
    _Float16* __restrict__ q_out, _Float16* __restrict__ k_out, _Float16* __restrict__ v_out,
    float* __restrict__ c_out,
    int M, int N, int K)
{
    __shared__ __attribute__((aligned(16))) _Float16 As[2 * 128 * 32];  // 16KB
    __shared__ __attribute__((aligned(16))) _Float16 Bs[2 * 128 * 32];  // 16KB

    const int tid  = threadIdx.x;
    const int lane = tid & 63;
    const int wave = tid >> 6;
    const int quad = lane >> 4;
    const int lc   = lane & 15;
    const int wr   = wave >> 1, wc = wave & 1;

    // T1 XCD-aware swizzle (bijective: nwg % 8 == 0)
    const int nwg = gridDim.x * gridDim.y;
    int flat = blockIdx.y * gridDim.x + blockIdx.x;
    flat = (flat & 7) * (nwg >> 3) + (flat >> 3);
    const size_t bm = (size_t)(flat / gridDim.x) * 128;
    const size_t bn = (size_t)(flat % gridDim.x) * 128;

    const int r0 = tid >> 2;        // 0..63
    const int ck = (tid & 3) * 8;   // 0,8,16,24

    const _Float16* Ap = A + (bm + r0) * (size_t)K + ck;
    const _Float16* Bp = Bw + (bn + r0) * (size_t)K + ck;
    _Float16* lA = As + tid * 8;
    _Float16* lB = Bs + tid * 8;
    const size_t rstep = (size_t)64 * K;

    floatx4 acc[4][4] = {};

    for (int kk = 0; kk < K; kk += 64) {
        __syncthreads();
        async_cp16(Ap + kk, lA);
        async_cp16(Ap + kk + rstep, lA + 2048);
        async_cp16(Ap + kk + 32, lA + 4096);
        async_cp16(Ap + kk + 32 + rstep, lA + 4096 + 2048);
        async_cp16(Bp + kk, lB);
        async_cp16(Bp + kk + rstep, lB + 2048);
        async_cp16(Bp + kk + 32, lB + 4096);
        async_cp16(Bp + kk + 32 + rstep, lB + 4096 + 2048);
        __syncthreads();

#pragma unroll
        for (int h = 0; h < 2; h++) {
            half8 af[4], bf[4];
#pragma unroll
            for (int mt = 0; mt < 4; mt++)
                af[mt] = *(const half8*)(As + h * 4096 + (wr * 64 + mt * 16 + lc) * 32 + quad * 8);
#pragma unroll
            for (int nt = 0; nt < 4; nt++)
                bf[nt] = *(const half8*)(Bs + h * 4096 + (wc * 64 + nt * 16 + lc) * 32 + quad * 8);
#pragma unroll
            for (int mt = 0; mt < 4; mt++)
#pragma unroll
                for (int nt = 0; nt < 4; nt++)
                    acc[mt][nt] = __builtin_amdgcn_mfma_f32_16x16x32_f16(af[mt], bf[nt], acc[mt][nt], 0, 0, 0);
        }
    }

#pragma unroll
    for (int mt = 0; mt < 4; mt++) {
        int mbase = (int)bm + wr * 64 + mt * 16 + quad * 4;
#pragma unroll
        for (int nt = 0; nt < 4; nt++) {
            int n = (int)bn + wc * 64 + nt * 16 + lc;
            float bv = bias[n];
#pragma unroll
            for (int r = 0; r < 4; r++) {
                float v = acc[mt][nt][r] + bv;
                int mm = mbase + r;
                if (EPI == 0) {
                    int seg = n >> 10;        // 0=Q 1=K 2=V
                    int cm  = n & 1023;
                    int h = cm >> 6, d = cm & 63;
                    int bb = mm >> 11, t = mm & 2047;
                    if (seg == 0) {
                        size_t dst = (((size_t)(bb * HH + h)) * TT + t) * HD + d;
                        q_out[dst] = (_Float16)(v * 0.18033688f);
                    } else if (seg == 1) {
                        size_t dst = (((size_t)(bb * HH + h)) * TT + t) * HD + d;
                        k_out[dst] = (_Float16)v;
                    } else {
                        // V transposed: [B*H, HD, T]
                        size_t dst = (((size_t)(bb * HH + h)) * HD + d) * TT + t;
                        v_out[dst] = (_Float16)v;
                    }
                } else {
                    c_out[(size_t)mm * N + n] = v;
                }
            }
        }
    }
}

// ---------------------------------------------------------------------------
// Flash attention, 32x32 MFMA structure. Grid (B*H, T/256), 512 thr = 8
// waves, 32 queries/wave, key tile = 64.
// Round 10: FULL ASYNC STAGING (T3/T4). K and V^T both staged via
// global_load_lds (pre-XOR'd source column, linear LDS dest), 3 LDS buffers,
// ONE raw s_barrier per tile, counted s_waitcnt vmcnt(2) (never 0 in steady
// state). Zero staging VALU, zero ds_writes, no reg prefetch round-trip.
// Ledger: prologue issues L0,L1 (2 cp each). Top of iter t: own outstanding
// = {L(t):2, L(t+1):2} -> vmcnt(2) drains exactly L(t); barrier publishes
// all waves' L(t); L(t+2) overwrites the buffer read in iter t-1 (safe:
// barrier at top of t orders those reads before this issue).
// ---------------------------------------------------------------------------
__global__ __launch_bounds__(512) void attn_flash(
    const _Float16* __restrict__ Qp, const _Float16* __restrict__ Kp,
    const _Float16* __restrict__ Vtp, _Float16* __restrict__ Op)
{
    __shared__ __attribute__((aligned(16))) _Float16 Ks[3][64 * 64];  // 3x8KB
    __shared__ __attribute__((aligned(16))) _Float16 Vs[3][64 * 64];  // 3x8KB, V^T [dim][key]

    const int bh   = blockIdx.x;   // 0..63 (b*16+h)
    const int qt   = blockIdx.y;   // 0..7
    const int tid  = threadIdx.x;
    const int lane = tid & 63;
    const int wave = tid >> 6;     // 0..7
    const int ql   = lane & 31;    // query (and dim-row id)
    const int hi   = lane >> 5;    // 0/1

    const size_t hb = (size_t)bh * TT * HD;  // == bh*HD*TT for V^T too

    const int qrow = qt * 256 + wave * 32 + ql;
    half8 bq[4];
#pragma unroll
    for (int c = 0; c < 4; c++)
        bq[c] = *(const half8*)(Qp + hb + (size_t)qrow * HD + c * 16 + hi * 8);

    floatx16 o0 = (floatx16)0.0f, o1 = (floatx16)0.0f;
    float mrun = -1e30f, lrun = 0.f;

    // staging maps (512 threads, 1 cp16 each per matrix per tile)
    const int srow = tid >> 3;                    // K: key row; V^T: dim row
    const int sgk  = (tid & 7) ^ (srow & 7);      // K swizzle f(row)=row&7
    const int sgv  = (tid & 7) ^ ((srow >> 2) & 7); // V swizzle f(row)=(row>>2)&7
    const _Float16* Kg = Kp  + hb + (size_t)srow * HD + sgk * 8;  // + kt*HD per tile
    const _Float16* Vg = Vtp + hb + (size_t)srow * TT + sgv * 8;  // + kt    per tile

    // clean vmcnt ledger: Q loads fully retired before first cp16
    asm volatile("s_waitcnt vmcnt(0)" ::: "memory");
    __builtin_amdgcn_sched_barrier(0);

    // prologue: tiles 0 and 1 in flight
    async_cp16(Kg,           Ks[0] + tid * 8);
    async_cp16(Vg,           Vs[0] + tid * 8);
    async_cp16(Kg + 64 * HD, Ks[1] + tid * 8);
    async_cp16(Vg + 64,      Vs[1] + tid * 8);

    const int NT = TT / 64;  // 32
    for (int t = 0; t < NT; ++t) {
        if (t < NT - 1) asm volatile("s_waitcnt vmcnt(2)" ::: "memory");
        else            asm volatile("s_waitcnt vmcnt(0)" ::: "memory");
        __builtin_amdgcn_s_barrier();
        __builtin_amdgcn_sched_barrier(0);

        if (t + 2 < NT) {
            const int q = (t + 2) - ((t + 2) / 3) * 3;  // (t+2)%3
            async_cp16(Kg + (size_t)(t + 2) * 64 * HD, Ks[q] + tid * 8);
            async_cp16(Vg + (t + 2) * 64,              Vs[q] + tid * 8);
        }
        __builtin_amdgcn_sched_barrier(0);

        const int cb = t - (t / 3) * 3;  // t%3
        const char* Kbuf = (const char*)Ks[cb];
        const char* Vbuf = (const char*)Vs[cb];

        // ---- S^T = K * Q^T : 2 key-blocks x 4 dim-chunks, 32x32x16 ----
        floatx16 s0 = (floatx16)0.0f, s1 = (floatx16)0.0f;
        __builtin_amdgcn_s_setprio(1);
#pragma unroll
        for (int c = 0; c < 4; c++) {
            int offk = (ql * 128 + c * 32 + hi * 16) ^ ((ql & 7) << 4);
            half8 a0 = *(const half8*)(Kbuf + offk);
            half8 a1 = *(const half8*)(Kbuf + offk + 4096);
            s0 = __builtin_amdgcn_mfma_f32_32x32x16_f16(a0, bq[c], s0, 0, 0, 0);
            s1 = __builtin_amdgcn_mfma_f32_32x32x16_f16(a1, bq[c], s1, 0, 0, 0);
        }
        __builtin_amdgcn_s_setprio(0);

        // ---- online softmax: per-lane 32 keys for query q=lane&31 ----
        float mx = fmaxf(maxv16(s0), maxv16(s1));
        mx = fmaxf(mx, __shfl_xor(mx, 32));
        const bool noresc = __all(mx <= mrun + 8.0f);
        const float mnew = noresc ? mrun : fmaxf(mrun, mx);
        float rs = 0.f;
        int d[16];
#pragma unroll
        for (int i = 0; i < 8; i++) {
            float e0 = exp2_raw(s0[2 * i] - mnew);
            float e1 = exp2_raw(s0[2 * i + 1] - mnew);
            rs += e0 + e1;
            d[i] = pkh(e0, e1);
        }
#pragma unroll
        for (int i = 0; i < 8; i++) {
            float e0 = exp2_raw(s1[2 * i] - mnew);
            float e1 = exp2_raw(s1[2 * i + 1] - mnew);
            rs += e0 + e1;
            d[8 + i] = pkh(e0, e1);
        }
        rs += __shfl_xor(rs, 32);
        if (!noresc) {
            float al = exp2_raw(mrun - mnew);
            mrun = mnew;
            lrun *= al;
            o0 *= al;
            o1 *= al;
        }
        lrun += rs;

        // ---- P^T B-frags: 16 keys each, via permlane32_swap ----
        half8 F[4];
        F[0] = assembleF(d[0], d[1], d[2], d[3]);
        F[1] = assembleF(d[4], d[5], d[6], d[7]);
        F[2] = assembleF(d[8], d[9], d[10], d[11]);
        F[3] = assembleF(d[12], d[13], d[14], d[15]);

        // ---- O^T += V^T * P^T : 2 dim-blocks x 4 key-chunks, 32x32x16 ----
        __builtin_amdgcn_s_setprio(1);
#pragma unroll
        for (int kb = 0; kb < 4; kb++) {
            int offv = (ql * 128 + kb * 32 + hi * 16) ^ (((ql >> 2) & 7) << 4);
            half8 v0 = *(const half8*)(Vbuf + offv);
            half8 v1 = *(const half8*)(Vbuf + offv + 4096);
            o0 = __builtin_amdgcn_mfma_f32_32x32x16_f16(v0, F[kb], o0, 0, 0, 0);
            o1 = __builtin_amdgcn_mfma_f32_32x32x16_f16(v1, F[kb], o1, 0, 0, 0);
        }
        __builtin_amdgcn_s_setprio(0);
    }

    // epilogue: O^T reg r (per dim-block) -> dim = (r&3) + 8*(r>>2) + 4*hi
    const float inv = __builtin_amdgcn_rcpf(lrun);
    const int b = bh >> 4, h = bh & 15;
    size_t base = ((size_t)(b * TT + qrow)) * CC + h * HD;
#pragma unroll
    for (int rr = 0; rr < 4; rr++) {
        half4 hv0, hv1;
#pragma unroll
        for (int t = 0; t < 4; t++) {
            hv0[t] = (_Float16)(o0[rr * 4 + t] * inv);
            hv1[t] = (_Float16)(o1[rr * 4 + t] * inv);
        }
        *(half4*)(Op + base + 8 * rr + 4 * hi) = hv0;
        *(half4*)(Op + base + 32 + 8 * rr + 4 * hi) = hv1;
    }
}

// ---------------------------------------------------------------------------
extern "C" void kernel_launch(void* const* d_in, const int* in_sizes, int n_in,
                              void* d_out, int out_size, void* d_ws, size_t ws_size,
                              hipStream_t stream) {
    const float* x      = (const float*)d_in[0];  // [B,T,C]
    const float* W_attn = (const float*)d_in[1];  // [3C,C]
    const float* b_attn = (const float*)d_in[2];  // [3C]
    const float* W_proj = (const float*)d_in[3];  // [C,C]
    const float* b_proj = (const float*)d_in[4];  // [C]
    float* out = (float*)d_out;

    const size_t SZ_XH  = (size_t)BB * TT * CC * 2;
    const size_t SZ_WA  = (size_t)3 * CC * CC * 2;
    const size_t SZ_WP  = (size_t)CC * CC * 2;
    const size_t SZ_QKV = (size_t)BB * HH * TT * HD * 2;
    size_t off = 0;
    _Float16* xh  = (_Float16*)((char*)d_ws + off); off += SZ_XH;
    _Float16* wah = (_Float16*)((char*)d_ws + off); off += SZ_WA;
    _Float16* wph = (_Float16*)((char*)d_ws + off); off += SZ_WP;
    _Float16* Qh  = (_Float16*)((char*)d_ws + off); off += SZ_QKV;
    _Float16* Kh  = (_Float16*)((char*)d_ws + off); off += SZ_QKV;
    _Float16* Vh  = (_Float16*)((char*)d_ws + off); off += SZ_QKV;  // V^T [B*H,HD,T]
    _Float16* Ah  = (_Float16*)((char*)d_ws + off); off += SZ_XH;
    if (ws_size < off) return;

    const int NTOT = NX + NWA + NWP;  // 12582912, /8/256 = 6144 blocks exact
    cvt_all<<<NTOT / 8 / 256, 256, 0, stream>>>(x, W_attn, W_proj, xh, wah, wph);

    hgemm_nt<0><<<dim3(3 * CC / 128, BB * TT / 128), 256, 0, stream>>>(
        xh, wah, b_attn, Qh, Kh, Vh, nullptr, BB * TT, 3 * CC, CC);

    attn_flash<<<dim3(BB * HH, TT / 256), 512, 0, stream>>>(Qh, Kh, Vh, Ah);

    hgemm_nt<1><<<dim3(CC / 128, BB * TT / 128), 256, 0, stream>>>(
        Ah, wph, b_proj, nullptr, nullptr, nullptr, out, BB * TT, CC, CC);
}

// Round 12
// 270.467 us; speedup vs baseline: 1.1045x; 1.1045x over previous
//
#include <hip/hip_runtime.h>
#include <hip/hip_bf16.h>

// Problem constants (B=4, T=2048, C=1024, H=16, HD=64)
#define BB 4
#define TT 2048
#define CC 1024
#define HH 16
#define HD 64

typedef _Float16 half8 __attribute__((ext_vector_type(8)));
typedef _Float16 half4 __attribute__((ext_vector_type(4)));
typedef _Float16 half2_t __attribute__((ext_vector_type(2)));
typedef __fp16 fp16x2 __attribute__((ext_vector_type(2)));
typedef float floatx4 __attribute__((ext_vector_type(4)));
typedef float floatx16 __attribute__((ext_vector_type(16)));
typedef int intx2 __attribute__((ext_vector_type(2)));
typedef int intx4 __attribute__((ext_vector_type(4)));

// async global->LDS, 16B per lane (dest = wave-uniform base + lane*16)
__device__ __forceinline__ void async_cp16(const void* g, void* l) {
    __builtin_amdgcn_global_load_lds(
        (const __attribute__((address_space(1))) unsigned int*)g,
        (__attribute__((address_space(3))) unsigned int*)l,
        16, 0, 0);
}

// raw v_exp_f32 — args <= 8 (defer-max THR) so no overflow; very negative
// args underflow to 0 in HW which is exactly softmax semantics.
__device__ __forceinline__ float exp2_raw(float x) {
    return __builtin_amdgcn_exp2f(x);
}

// pack 2 f32 -> dword of 2 fp16 via v_cvt_pkrtz
__device__ __forceinline__ int pkh(float a, float b) {
    fp16x2 v = __builtin_amdgcn_cvt_pkrtz(a, b);
    return __builtin_bit_cast(int, v);
}

// max over a f32x16 accumulator, max3-friendly
__device__ __forceinline__ float maxv16(floatx16 s) {
    float a0 = fmaxf(fmaxf(s[0], s[1]), s[2]);
    float a1 = fmaxf(fmaxf(s[3], s[4]), s[5]);
    float a2 = fmaxf(fmaxf(s[6], s[7]), s[8]);
    float a3 = fmaxf(fmaxf(s[9], s[10]), s[11]);
    float a4 = fmaxf(fmaxf(s[12], s[13]), s[14]);
    float b0 = fmaxf(fmaxf(a0, a1), a2);
    float b1 = fmaxf(fmaxf(a3, a4), s[15]);
    return fmaxf(b0, b1);
}

// Assemble one 16-key B-frag (32x32x16, 8 fp16) from 4 cvtpk dwords.
// (verified rounds 5-10: passes absmax)
__device__ __forceinline__ half8 assembleF(int a, int b, int c, int d) {
    intx2 s1 = __builtin_amdgcn_permlane32_swap(a, c, false, false);
    intx2 s2 = __builtin_amdgcn_permlane32_swap(b, d, false, false);
    intx4 w = {s1[0], s2[0], s1[1], s2[1]};
    return __builtin_bit_cast(half8, w);
}

// ---------------------------------------------------------------------------
// fused fp32 -> fp16 conversion for x, W_attn, W_proj in ONE launch.
// ---------------------------------------------------------------------------
#define NX  (BB * TT * CC)        // 8388608
#define NWA (3 * CC * CC)         // 3145728
#define NWP (CC * CC)             // 1048576
__global__ void cvt_all(const float* __restrict__ x, const float* __restrict__ wa,
                        const float* __restrict__ wp,
                        _Float16* __restrict__ xh, _Float16* __restrict__ wah,
                        _Float16* __restrict__ wph) {
    int i = (blockIdx.x * blockDim.x + threadIdx.x) * 8;
    const float* src;
    _Float16* dst;
    int j;
    if (i < NX)            { src = x;  dst = xh;  j = i; }
    else if (i < NX + NWA) { src = wa; dst = wah; j = i - NX; }
    else                   { src = wp; dst = wph; j = i - NX - NWA; }
    float4 v0 = *(const float4*)(src + j);
    float4 v1 = *(const float4*)(src + j + 4);
    half8 h;
    h[0] = (_Float16)v0.x; h[1] = (_Float16)v0.y; h[2] = (_Float16)v0.z; h[3] = (_Float16)v0.w;
    h[4] = (_Float16)v1.x; h[5] = (_Float16)v1.y; h[6] = (_Float16)v1.z; h[7] = (_Float16)v1.w;
    *(half8*)(dst + j) = h;
}

// ---------------------------------------------------------------------------
// QKV GEMM: 8-phase 256x256 schedule (T2+T3+T4+T5), CROSS-WAVE-SAFE vmcnt.
// Invariant (round-11 fix): every counted vmcnt that covers a tile's loads
// executes BEFORE a barrier that precedes the first ds_read of that tile
// (writer-drain -> barrier -> read). vmcnt(4) sits at the END of P3 / P7,
// just before that phase's closing s_barrier.
//
// 512 thr = 8 waves (2M x 4N); per-wave C: rows mq*128+wr*64+mt*16,
// cols nq*128+wn*32+nt*16 -> each phase reads exactly one A-half + one
// B-half. LDS 128KB: 2 buf x (A 256x64 + B 256x64); buf0 even K-tiles,
// buf1 odd. BK=64, 16 K-tiles, 8 iters x 8 phases.
// Ledger (steady state, 2 cp16 per STG):
//   end-P3: outstanding 12 -> vmcnt(4) drains tile 2i+1 (8 oldest) -> barrier
//           -> P4-P7 read buf1 safely. (i==7: vmcnt(0), 8 outstanding = tile15)
//   end-P7: outstanding 12 -> vmcnt(4) drains tile 2i+2 -> barrier ->
//           next iter's P0-P3 read buf0 safely.
// Prologue: 12 issued, vmcnt(4) drains tile0, barrier publishes.
// Same-phase RD/STG never touch the same half (verified per phase).
// Staging/swizzle/frag/epilogue math identical to round-8 verified kernel.
// ---------------------------------------------------------------------------
__global__ __launch_bounds__(512, 1) void qkv8ph(
    const _Float16* __restrict__ A, const _Float16* __restrict__ Bw,
    const float* __restrict__ bias,
    _Float16* __restrict__ q_out, _Float16* __restrict__ k_out, _Float16* __restrict__ v_out)
{
    __shared__ __attribute__((aligned(16))) _Float16 LA[2 * 256 * 64];  // 64KB
    __shared__ __attribute__((aligned(16))) _Float16 LB[2 * 256 * 64];  // 64KB

    const int tid  = threadIdx.x;
    const int lane = tid & 63;
    const int wave = tid >> 6;
    const int quad = lane >> 4;
    const int lc   = lane & 15;
    const int wr   = wave >> 2;   // 0..1 (M)
    const int wn   = wave & 3;    // 0..3 (N)

    // T1 bijective remap (nwg = 384, 384%8==0)
    int flat = blockIdx.y * gridDim.x + blockIdx.x;
    flat = (flat & 7) * 48 + (flat >> 3);
    const size_t bm = (size_t)(flat / 12) * 256;
    const size_t bn = (size_t)(flat % 12) * 256;

    // staging: row = tid>>3 (0..63) within 64-row block, chunk pre-swizzled
    const int srow = tid >> 3;
    const int sch  = (tid & 7) ^ (srow & 7);
    const _Float16* Asrc = A  + (bm + srow) * (size_t)CC + sch * 8;
    const _Float16* Bsrc = Bw + (bn + srow) * (size_t)CC + sch * 8;
    const int xr = lc & 7;

    floatx4 acc[2][4][2][2] = {};
    half8 af[4][2], bf[2][2];

#define STG_A(BOFF, H, T) do { if ((T) < 16) {                                        \
        async_cp16(Asrc + (size_t)((H) * 128) * CC + (T) * 64,                        \
                   LA + (BOFF) + (H) * 8192 + tid * 8);                               \
        async_cp16(Asrc + (size_t)((H) * 128 + 64) * CC + (T) * 64,                   \
                   LA + (BOFF) + (H) * 8192 + 4096 + tid * 8); } } while (0)
#define STG_B(BOFF, H, T) do { if ((T) < 16) {                                        \
        async_cp16(Bsrc + (size_t)((H) * 128) * CC + (T) * 64,                        \
                   LB + (BOFF) + (H) * 8192 + tid * 8);                               \
        async_cp16(Bsrc + (size_t)((H) * 128 + 64) * CC + (T) * 64,                   \
                   LB + (BOFF) + (H) * 8192 + 4096 + tid * 8); } } while (0)
#define RD_A(BOFF, MQ) do {                                                           \
        _Pragma("unroll") for (int mt = 0; mt < 4; mt++) {                            \
            int row = (MQ) * 128 + wr * 64 + mt * 16 + lc;                            \
            _Pragma("unroll") for (int kh = 0; kh < 2; kh++)                          \
                af[mt][kh] = *(const half8*)(LA + (BOFF) + row * 64 +                 \
                                             ((kh * 4 + quad) ^ xr) * 8);             \
        } } while (0)
#define RD_B(BOFF, NQ) do {                                                           \
        _Pragma("unroll") for (int nt = 0; nt < 2; nt++) {                            \
            int row = (NQ) * 128 + wn * 32 + nt * 16 + lc;                            \
            _Pragma("unroll") for (int kh = 0; kh < 2; kh++)                          \
                bf[nt][kh] = *(const half8*)(LB + (BOFF) + row * 64 +                 \
                                             ((kh * 4 + quad) ^ xr) * 8);             \
        } } while (0)
#define DO_MFMA(MQ, NQ) do {                                                          \
        __builtin_amdgcn_s_setprio(1);                                                \
        _Pragma("unroll") for (int mt = 0; mt < 4; mt++)                              \
        _Pragma("unroll") for (int nt = 0; nt < 2; nt++) {                            \
            acc[MQ][mt][NQ][nt] = __builtin_amdgcn_mfma_f32_16x16x32_f16(             \
                af[mt][0], bf[nt][0], acc[MQ][mt][NQ][nt], 0, 0, 0);                  \
            acc[MQ][mt][NQ][nt] = __builtin_amdgcn_mfma_f32_16x16x32_f16(             \
                af[mt][1], bf[nt][1], acc[MQ][mt][NQ][nt], 0, 0, 0);                  \
        }                                                                             \
        __builtin_amdgcn_s_setprio(0);                                                \
    } while (0)
#define MIDBAR() do { __builtin_amdgcn_s_barrier();                                   \
        asm volatile("s_waitcnt lgkmcnt(0)" ::: "memory");                            \
        __builtin_amdgcn_sched_barrier(0); } while (0)
#define ENDBAR() __builtin_amdgcn_s_barrier()
#define VMW(N) do { asm volatile("s_waitcnt vmcnt(" #N ")" ::: "memory");             \
        __builtin_amdgcn_sched_barrier(0); } while (0)

    // prologue: tile0 complete (buf0) + tile1 Ah0/Bh1 (buf1); drain tile0,
    // barrier publishes it to all waves before any read.
    STG_A(0, 0, 0); STG_A(0, 1, 0); STG_B(0, 0, 0); STG_B(0, 1, 0);
    STG_A(16384, 0, 1); STG_B(16384, 1, 1);
    VMW(4);
    __builtin_amdgcn_s_barrier();

#pragma unroll 1
    for (int i = 0; i < 8; ++i) {
        const int tb = 2 * i + 1, ta2 = 2 * i + 2, tb2 = 2 * i + 3;
        // P0: (m0,n0) of buf0 (tile 2i: drained+published at end of prev P7)
        RD_A(0, 0); RD_B(0, 0); STG_A(16384, 1, tb);
        MIDBAR(); DO_MFMA(0, 0); ENDBAR();
        // P1: (m0,n1)
        RD_B(0, 1); STG_B(16384, 0, tb);
        MIDBAR(); DO_MFMA(0, 1); ENDBAR();
        // P2: (m1,n1)  (af reloaded, bf reused)
        RD_A(0, 1); STG_A(0, 0, ta2);
        MIDBAR(); DO_MFMA(1, 1); ENDBAR();
        // P3: (m1,n0) + drain tile 2i+1 BEFORE the closing barrier
        RD_B(0, 0); STG_B(0, 1, ta2);
        MIDBAR(); DO_MFMA(1, 0);
        if (i < 7) { VMW(4); } else { VMW(0); }
        ENDBAR();
        // P4: (m0,n0) of buf1 (tile 2i+1: drained+published at end of P3)
        RD_A(16384, 0); RD_B(16384, 0); STG_A(0, 1, ta2);
        MIDBAR(); DO_MFMA(0, 0); ENDBAR();
        // P5: (m0,n1)
        RD_B(16384, 1); STG_B(0, 0, ta2);
        MIDBAR(); DO_MFMA(0, 1); ENDBAR();
        // P6: (m1,n1)
        RD_A(16384, 1); STG_A(16384, 0, tb2);
        MIDBAR(); DO_MFMA(1, 1); ENDBAR();
        // P7: (m1,n0) + drain tile 2i+2 BEFORE the closing barrier
        RD_B(16384, 0); STG_B(16384, 1, tb2);
        MIDBAR(); DO_MFMA(1, 0);
        if (i < 7) { VMW(4); }
        ENDBAR();
    }
#undef STG_A
#undef STG_B
#undef RD_A
#undef RD_B
#undef DO_MFMA
#undef MIDBAR
#undef ENDBAR
#undef VMW

    // epilogue: scatter -> Q(scaled 0.125*log2e)/K/V fp16 [B*H, T, 64]
#pragma unroll
    for (int mq = 0; mq < 2; mq++)
#pragma unroll
    for (int mt = 0; mt < 4; mt++) {
        int mbase = (int)bm + mq * 128 + wr * 64 + mt * 16 + quad * 4;
#pragma unroll
        for (int nq = 0; nq < 2; nq++)
#pragma unroll
        for (int nt = 0; nt < 2; nt++) {
            int n = (int)bn + nq * 128 + wn * 32 + nt * 16 + lc;
            float bv = bias[n];
#pragma unroll
            for (int r = 0; r < 4; r++) {
                float v = acc[mq][mt][nq][nt][r] + bv;
                int mm = mbase + r;
                int seg = n >> 10;        // 0=Q 1=K 2=V
                int cm  = n & 1023;
                int hh = cm >> 6, d = cm & 63;
                int b2 = mm >> 11, t = mm & 2047;
                size_t dst = (((size_t)(b2 * HH + hh)) * TT + t) * HD + d;
                if (seg == 0)      q_out[dst] = (_Float16)(v * 0.18033688f);
                else if (seg == 1) k_out[dst] = (_Float16)v;
                else               v_out[dst] = (_Float16)v;
            }
        }
    }
}

// ---------------------------------------------------------------------------
// proj GEMM: 128x128 tile, BK=64 + T1 (round-9 proven), fp32 out
// ---------------------------------------------------------------------------
__global__ __launch_bounds__(256) void hgemm_proj(
    const _Float16* __restrict__ A, const _Float16* __restrict__ Bw,
    const float* __restrict__ bias, float* __restrict__ c_out,
    int M, int N, int K)
{
    __shared__ __attribute__((aligned(16))) _Float16 As[2 * 128 * 32];  // 16KB
    __shared__ __attribute__((aligned(16))) _Float16 Bs[2 * 128 * 32];  // 16KB

    const int tid  = threadIdx.x;
    const int lane = tid & 63;
    const int wave = tid >> 6;
    const int quad = lane >> 4;
    const int lc   = lane & 15;
    const int wr   = wave >> 1, wc = wave & 1;

    const int nwg = gridDim.x * gridDim.y;
    int flat = blockIdx.y * gridDim.x + blockIdx.x;
    flat = (flat & 7) * (nwg >> 3) + (flat >> 3);
    const size_t bm = (size_t)(flat / gridDim.x) * 128;
    const size_t bn = (size_t)(flat % gridDim.x) * 128;

    const int r0 = tid >> 2;
    const int ck = (tid & 3) * 8;

    const _Float16* Ap = A + (bm + r0) * (size_t)K + ck;
    const _Float16* Bp = Bw + (bn + r0) * (size_t)K + ck;
    _Float16* lA = As + tid * 8;
    _Float16* lB = Bs + tid * 8;
    const size_t rstep = (size_t)64 * K;

    floatx4 acc[4][4] = {};

    for (int kk = 0; kk < K; kk += 64) {
        __syncthreads();
        async_cp16(Ap + kk, lA);
        async_cp16(Ap + kk + rstep, lA + 2048);
        async_cp16(Ap + kk + 32, lA + 4096);
        async_cp16(Ap + kk + 32 + rstep, lA + 4096 + 2048);
        async_cp16(Bp + kk, lB);
        async_cp16(Bp + kk + rstep, lB + 2048);
        async_cp16(Bp + kk + 32, lB + 4096);
        async_cp16(Bp + kk + 32 + rstep, lB + 4096 + 2048);
        __syncthreads();

#pragma unroll
        for (int h = 0; h < 2; h++) {
            half8 af[4], bf[4];
#pragma unroll
            for (int mt = 0; mt < 4; mt++)
                af[mt] = *(const half8*)(As + h * 4096 + (wr * 64 + mt * 16 + lc) * 32 + quad * 8);
#pragma unroll
            for (int nt = 0; nt < 4; nt++)
                bf[nt] = *(const half8*)(Bs + h * 4096 + (wc * 64 + nt * 16 + lc) * 32 + quad * 8);
#pragma unroll
            for (int mt = 0; mt < 4; mt++)
#pragma unroll
                for (int nt = 0; nt < 4; nt++)
                    acc[mt][nt] = __builtin_amdgcn_mfma_f32_16x16x32_f16(af[mt], bf[nt], acc[mt][nt], 0, 0, 0);
        }
    }

#pragma unroll
    for (int mt = 0; mt < 4; mt++) {
        int mbase = (int)bm + wr * 64 + mt * 16 + quad * 4;
#pragma unroll
        for (int nt = 0; nt < 4; nt++) {
            int n = (int)bn + wc * 64 + nt * 16 + lc;
            float bv = bias[n];
#pragma unroll
            for (int r = 0; r < 4; r++)
                c_out[(size_t)(mbase + r) * N + n] = acc[mt][nt][r] + bv;
        }
    }
}

// ---------------------------------------------------------------------------
// Flash attention, 32x32 MFMA, double-buffered reg-staged (round-9 proven).
// ---------------------------------------------------------------------------
__global__ __launch_bounds__(512) void attn_flash(
    const _Float16* __restrict__ Qp, const _Float16* __restrict__ Kp,
    const _Float16* __restrict__ Vp, _Float16* __restrict__ Op)
{
    __shared__ __attribute__((aligned(16))) _Float16 Ks[2][64 * 64];  // 2x8KB
    __shared__ __attribute__((aligned(16))) _Float16 Vt[2][64 * 64];  // 2x8KB

    const int bh   = blockIdx.x;
    const int qt   = blockIdx.y;
    const int tid  = threadIdx.x;
    const int lane = tid & 63;
    const int wave = tid >> 6;
    const int ql   = lane & 31;
    const int hi   = lane >> 5;

    const size_t hb = (size_t)bh * TT * HD;

    const int qrow = qt * 256 + wave * 32 + ql;
    half8 bq[4];
#pragma unroll
    for (int c = 0; c < 4; c++)
        bq[c] = *(const half8*)(Qp + hb + (size_t)qrow * HD + c * 16 + hi * 8);

    floatx16 o0 = (floatx16)0.0f, o1 = (floatx16)0.0f;
    float mrun = -1e30f, lrun = 0.f;

    const int sk = tid >> 3;
    const int sj = tid & 7;
    const int sg = sj ^ (sk & 7);
    const _Float16* Kg = Kp + hb + (size_t)sk * HD + sg * 8;

    const int vkp = tid >> 4;
    const int vd4 = (tid & 15) * 4;
    const _Float16* Vg0 = Vp + hb + (size_t)(2 * vkp) * HD + vd4;
    const _Float16* Vg1 = Vg0 + HD;

    half8 kv  = *(const half8*)Kg;
    half4 va0 = *(const half4*)Vg0;
    half4 vb0 = *(const half4*)Vg1;
    *(half8*)(Ks[0] + tid * 8) = kv;
#pragma unroll
    for (int j = 0; j < 4; j++) {
        int row = vd4 + j;
        int boff = (row * 128 + vkp * 4) ^ (((row >> 2) & 7) << 4);
        half2_t w; w[0] = va0[j]; w[1] = vb0[j];
        *(half2_t*)((char*)Vt[0] + boff) = w;
    }
    {
        const size_t koff = (size_t)64 * HD;
        kv  = *(const half8*)(Kg + koff);
        va0 = *(const half4*)(Vg0 + koff);
        vb0 = *(const half4*)(Vg1 + koff);
    }

    int cur = 0;
    for (int kt = 0; kt < TT; kt += 64) {
        __syncthreads();

        if (kt + 64 < TT) {
            *(half8*)(Ks[cur ^ 1] + tid * 8) = kv;
#pragma unroll
            for (int j = 0; j < 4; j++) {
                int row = vd4 + j;
                int boff = (row * 128 + vkp * 4) ^ (((row >> 2) & 7) << 4);
                half2_t w; w[0] = va0[j]; w[1] = vb0[j];
                *(half2_t*)((char*)Vt[cur ^ 1] + boff) = w;
            }
            if (kt + 128 < TT) {
                const size_t koff = (size_t)(kt + 128) * HD;
                kv  = *(const half8*)(Kg + koff);
                va0 = *(const half4*)(Vg0 + koff);
                vb0 = *(const half4*)(Vg1 + koff);
            }
        }

        const char* Kbuf = (const char*)Ks[cur];
        const char* Vbuf = (const char*)Vt[cur];

        floatx16 s0 = (floatx16)0.0f, s1 = (floatx16)0.0f;
        __builtin_amdgcn_s_setprio(1);
#pragma unroll
        for (int c = 0; c < 4; c++) {
            int offk = (ql * 128 + c * 32 + hi * 16) ^ ((ql & 7) << 4);
            half8 a0 = *(const half8*)(Kbuf + offk);
            half8 a1 = *(const half8*)(Kbuf + offk + 4096);
            s0 = __builtin_amdgcn_mfma_f32_32x32x16_f16(a0, bq[c], s0, 0, 0, 0);
            s1 = __builtin_amdgcn_mfma_f32_32x32x16_f16(a1, bq[c], s1, 0, 0, 0);
        }
        __builtin_amdgcn_s_setprio(0);

        float mx = fmaxf(maxv16(s0), maxv16(s1));
        mx = fmaxf(mx, __shfl_xor(mx, 32));
        const bool noresc = __all(mx <= mrun + 8.0f);
        const float mnew = noresc ? mrun : fmaxf(mrun, mx);
        float rs = 0.f;
        int d[16];
#pragma unroll
        for (int i = 0; i < 8; i++) {
            float e0 = exp2_raw(s0[2 * i] - mnew);
            float e1 = exp2_raw(s0[2 * i + 1] - mnew);
            rs += e0 + e1;
            d[i] = pkh(e0, e1);
        }
#pragma unroll
        for (int i = 0; i < 8; i++) {
            float e0 = exp2_raw(s1[2 * i] - mnew);
            float e1 = exp2_raw(s1[2 * i + 1] - mnew);
            rs += e0 + e1;
            d[8 + i] = pkh(e0, e1);
        }
        rs += __shfl_xor(rs, 32);
        if (!noresc) {
            float al = exp2_raw(mrun - mnew);
            mrun = mnew;
            lrun *= al;
            o0 *= al;
            o1 *= al;
        }
        lrun += rs;

        half8 F[4];
        F[0] = assembleF(d[0], d[1], d[2], d[3]);
        F[1] = assembleF(d[4], d[5], d[6], d[7]);
        F[2] = assembleF(d[8], d[9], d[10], d[11]);
        F[3] = assembleF(d[12], d[13], d[14], d[15]);

        __builtin_amdgcn_s_setprio(1);
#pragma unroll
        for (int kb = 0; kb < 4; kb++) {
            int offv = (ql * 128 + kb * 32 + hi * 16) ^ (((ql >> 2) & 7) << 4);
            half8 v0 = *(const half8*)(Vbuf + offv);
            half8 v1 = *(const half8*)(Vbuf + offv + 4096);
            o0 = __builtin_amdgcn_mfma_f32_32x32x16_f16(v0, F[kb], o0, 0, 0, 0);
            o1 = __builtin_amdgcn_mfma_f32_32x32x16_f16(v1, F[kb], o1, 0, 0, 0);
        }
        __builtin_amdgcn_s_setprio(0);

        cur ^= 1;
    }

    const float inv = __builtin_amdgcn_rcpf(lrun);
    const int b = bh >> 4, h = bh & 15;
    size_t base = ((size_t)(b * TT + qrow)) * CC + h * HD;
#pragma unroll
    for (int rr = 0; rr < 4; rr++) {
        half4 hv0, hv1;
#pragma unroll
        for (int t = 0; t < 4; t++) {
            hv0[t] = (_Float16)(o0[rr * 4 + t] * inv);
            hv1[t] = (_Float16)(o1[rr * 4 + t] * inv);
        }
        *(half4*)(Op + base + 8 * rr + 4 * hi) = hv0;
        *(half4*)(Op + base + 32 + 8 * rr + 4 * hi) = hv1;
    }
}

// ---------------------------------------------------------------------------
extern "C" void kernel_launch(void* const* d_in, const int* in_sizes, int n_in,
                              void* d_out, int out_size, void* d_ws, size_t ws_size,
                              hipStream_t stream) {
    const float* x      = (const float*)d_in[0];  // [B,T,C]
    const float* W_attn = (const float*)d_in[1];  // [3C,C]
    const float* b_attn = (const float*)d_in[2];  // [3C]
    const float* W_proj = (const float*)d_in[3];  // [C,C]
    const float* b_proj = (const float*)d_in[4];  // [C]
    float* out = (float*)d_out;

    const size_t SZ_XH  = (size_t)BB * TT * CC * 2;
    const size_t SZ_WA  = (size_t)3 * CC * CC * 2;
    const size_t SZ_WP  = (size_t)CC * CC * 2;
    const size_t SZ_QKV = (size_t)BB * HH * TT * HD * 2;
    size_t off = 0;
    _Float16* xh  = (_Float16*)((char*)d_ws + off); off += SZ_XH;
    _Float16* wah = (_Float16*)((char*)d_ws + off); off += SZ_WA;
    _Float16* wph = (_Float16*)((char*)d_ws + off); off += SZ_WP;
    _Float16* Qh  = (_Float16*)((char*)d_ws + off); off += SZ_QKV;
    _Float16* Kh  = (_Float16*)((char*)d_ws + off); off += SZ_QKV;
    _Float16* Vh  = (_Float16*)((char*)d_ws + off); off += SZ_QKV;
    _Float16* Ah  = (_Float16*)((char*)d_ws + off); off += SZ_XH;
    if (ws_size < off) return;

    const int NTOT = NX + NWA + NWP;  // 12582912, /8/256 = 6144 blocks exact
    cvt_all<<<NTOT / 8 / 256, 256, 0, stream>>>(x, W_attn, W_proj, xh, wah, wph);

    qkv8ph<<<dim3(12, 32), 512, 0, stream>>>(xh, wah, b_attn, Qh, Kh, Vh);

    attn_flash<<<dim3(BB * HH, TT / 256), 512, 0, stream>>>(Qh, Kh, Vh, Ah);

    hgemm_proj<<<dim3(CC / 128, BB * TT / 128), 256, 0, stream>>>(
        Ah, wph, b_proj, out, BB * TT, CC, CC);
}